// Round 2
// baseline (694.607 us; speedup 1.0000x reference)
//
#include <hip/hip_runtime.h>
#include <math.h>

// Problem constants (fixed by reference)
#define WDIM 8
#define WPDIM 10
#define WWDIM 64          // 8*8
#define CDIM 128
#define CF 120            // C - SLICE
#define NTHREADS 320
#define LDA 129           // pad 128 -> 129 (129 % 32 == 1, conflict-free)
#define LDB 129
#define LDC 101           // pad 100 -> 101

__global__ __launch_bounds__(NTHREADS) void fine_matching_kernel(
    const float* __restrict__ feat0,   // [M][64][128]
    const float* __restrict__ feat1,   // [M][100][128]
    const float* __restrict__ mkpts0,  // [Nm][2]
    const float* __restrict__ mkpts1,  // [Nm][2]
    const float* __restrict__ expec0,  // [M][2]
    const float* __restrict__ expec1,  // [M][2]
    float* __restrict__ out,           // 4*Nm + 4*M floats
    int M, int Nm)
{
    __shared__ float Asm[64 * LDA];      // feat0[m], padded rows
    __shared__ float Bsm[100 * LDB];     // feat1[m], padded rows
    __shared__ float Csm[64 * LDC];      // conf_f
    __shared__ float rm[64], irs[64];    // row (axis=2) stats: max, 1/sum
    __shared__ float cm[100], ics[100];  // col (axis=1) stats
    __shared__ float redV[NTHREADS];
    __shared__ int   redQ[NTHREADS];
    __shared__ float win[18];            // [0..8]=cff window, [9..17]=cffr window
    __shared__ float cxy[4];             // (cx,cy) for cff-window, cffr-window
    __shared__ int   bestLK[2];

    const int m = blockIdx.x;
    const int tid = threadIdx.x;
    const float* f0 = feat0 + (size_t)m * (64 * 128);
    const float* f1 = feat1 + (size_t)m * (100 * 128);

    // ---- stage feat0 / feat1 into LDS (padded rows) ----
    for (int w4 = tid; w4 < 64 * 128 / 4; w4 += NTHREADS) {
        float4 v = ((const float4*)f0)[w4];
        int w = w4 * 4;
        int row = w >> 7, col = w & 127;
        float* p = &Asm[row * LDA + col];
        p[0] = v.x; p[1] = v.y; p[2] = v.z; p[3] = v.w;
    }
    for (int w4 = tid; w4 < 100 * 128 / 4; w4 += NTHREADS) {
        float4 v = ((const float4*)f1)[w4];
        int w = w4 * 4;
        int row = w >> 7, col = w & 127;
        float* p = &Bsm[row * LDB + col];
        p[0] = v.x; p[1] = v.y; p[2] = v.z; p[3] = v.w;
    }
    __syncthreads();

    // ---- conf_f = (A[64x120] . B[100x120]^T) / 128 ; 4x5 register tile ----
    {
        const int lg = tid / 20, rg = tid % 20;   // 16 x 20 thread grid
        const int l0 = lg * 4, r0 = rg * 5;
        float acc[4][5];
        #pragma unroll
        for (int a = 0; a < 4; a++)
            #pragma unroll
            for (int b = 0; b < 5; b++) acc[a][b] = 0.0f;

        const float* Ap = &Asm[l0 * LDA];
        const float* Bp = &Bsm[r0 * LDB];
        for (int c = 0; c < CF; c++) {
            float a0 = Ap[c], a1 = Ap[LDA + c], a2 = Ap[2 * LDA + c], a3 = Ap[3 * LDA + c];
            float b0 = Bp[c], b1 = Bp[LDB + c], b2 = Bp[2 * LDB + c],
                  b3 = Bp[3 * LDB + c], b4 = Bp[4 * LDB + c];
            acc[0][0] = fmaf(a0, b0, acc[0][0]);
            acc[0][1] = fmaf(a0, b1, acc[0][1]);
            acc[0][2] = fmaf(a0, b2, acc[0][2]);
            acc[0][3] = fmaf(a0, b3, acc[0][3]);
            acc[0][4] = fmaf(a0, b4, acc[0][4]);
            acc[1][0] = fmaf(a1, b0, acc[1][0]);
            acc[1][1] = fmaf(a1, b1, acc[1][1]);
            acc[1][2] = fmaf(a1, b2, acc[1][2]);
            acc[1][3] = fmaf(a1, b3, acc[1][3]);
            acc[1][4] = fmaf(a1, b4, acc[1][4]);
            acc[2][0] = fmaf(a2, b0, acc[2][0]);
            acc[2][1] = fmaf(a2, b1, acc[2][1]);
            acc[2][2] = fmaf(a2, b2, acc[2][2]);
            acc[2][3] = fmaf(a2, b3, acc[2][3]);
            acc[2][4] = fmaf(a2, b4, acc[2][4]);
            acc[3][0] = fmaf(a3, b0, acc[3][0]);
            acc[3][1] = fmaf(a3, b1, acc[3][1]);
            acc[3][2] = fmaf(a3, b2, acc[3][2]);
            acc[3][3] = fmaf(a3, b3, acc[3][3]);
            acc[3][4] = fmaf(a3, b4, acc[3][4]);
        }
        const float sc = 1.0f / 128.0f;
        #pragma unroll
        for (int a = 0; a < 4; a++)
            #pragma unroll
            for (int b = 0; b < 5; b++)
                Csm[(l0 + a) * LDC + (r0 + b)] = acc[a][b] * sc;
    }
    __syncthreads();

    // ---- dual-softmax stats ----
    if (tid < 64) {
        // softmax over r (axis=2): per row l = tid
        const float* row = &Csm[tid * LDC];
        float mx = row[0];
        for (int r = 1; r < 100; r++) mx = fmaxf(mx, row[r]);
        float s = 0.0f;
        for (int r = 0; r < 100; r++) s += expf(row[r] - mx);
        rm[tid] = mx; irs[tid] = 1.0f / s;
    } else if (tid < 164) {
        // softmax over l (axis=1): per column r = tid - 64
        const int r = tid - 64;
        float mx = Csm[r];
        for (int l = 1; l < 64; l++) mx = fmaxf(mx, Csm[l * LDC + r]);
        float s = 0.0f;
        for (int l = 0; l < 64; l++) s += expf(Csm[l * LDC + r] - mx);
        cm[r] = mx; ics[r] = 1.0f / s;
    }
    __syncthreads();

    // ---- argmax over interior 64x64 of sm = softmax_l * softmax_r ----
    // sm[l][r] = exp(x - rm[l])*irs[l] * exp(x - cm[r])*ics[r]
    //          = exp(2x - rm[l] - cm[r]) * irs[l] * ics[r]
    {
        float bv = -INFINITY;
        int bq = 1 << 30;
        for (int q = tid; q < 4096; q += NTHREADS) {
            int l = q >> 6, k = q & 63;
            int r = (k >> 3) * 10 + (k & 7) + 11;   // (i+1)*10 + (j+1)
            float x = Csm[l * LDC + r];
            float v = expf(2.0f * x - rm[l] - cm[r]) * irs[l] * ics[r];
            if (v > bv) { bv = v; bq = q; }   // ascending q => first-index tiebreak
        }
        redV[tid] = bv; redQ[tid] = bq;
    }
    __syncthreads();
    if (tid < 64) {
        float bv = redV[tid]; int bq = redQ[tid];
        for (int i = tid + 64; i < NTHREADS; i += 64) {
            float v = redV[i]; int q = redQ[i];
            if (v > bv || (v == bv && q < bq)) { bv = v; bq = q; }
        }
        #pragma unroll
        for (int off = 32; off > 0; off >>= 1) {
            float v = __shfl_xor(bv, off);
            int q = __shfl_xor(bq, off);
            if (v > bv || (v == bv && q < bq)) { bv = v; bq = q; }
        }
        if (tid == 0) { bestLK[0] = bq >> 6; bestLK[1] = bq & 63; }
    }
    __syncthreads();

    // ---- 3x3 local windows on tail channels (120..127) ----
    const int il = bestLK[0], ir = bestLK[1];
    if (tid < 18) {
        const int wsel = tid / 9, e = tid % 9;
        const int dy = e / 3 - 1, dx = e % 3 - 1;
        float val = 0.0f;
        if (wsel == 0) {
            // cff[m, il, ii, jj]: dot8(feat0[il], feat1[ii*10+jj])
            int ii = (ir / 8 + dy + 10) % 10;
            int jj = (ir % 8 + dx + 10) % 10;
            const float* pa = &Asm[il * LDA + CF];
            const float* pb = &Bsm[(ii * 10 + jj) * LDB + CF];
            #pragma unroll
            for (int c = 0; c < 8; c++) val = fmaf(pa[c], pb[c], val);
        } else {
            // cffr[m, ir, ii, jj] = conf_ff_rev flat [ir*100 + ii*10 + jj]
            int ii = (il / 8 + dy + 10) % 10;
            int jj = (il % 8 + dx + 10) % 10;
            int p = ir * 100 + ii * 10 + jj;
            const float* pa = &Bsm[(p >> 6) * LDB + CF];
            const float* pb = &Asm[(p & 63) * LDA + CF];
            #pragma unroll
            for (int c = 0; c < 8; c++) val = fmaf(pa[c], pb[c], val);
        }
        win[tid] = val * 0.35355339059327373f;   // 1/sqrt(8)
    }
    __syncthreads();
    if (tid < 2) {
        const float* wv = &win[tid * 9];
        float t[9]; float mx = -INFINITY;
        #pragma unroll
        for (int e = 0; e < 9; e++) { t[e] = wv[e] * 0.1f; mx = fmaxf(mx, t[e]); }
        float s = 0.0f, sx = 0.0f, sy = 0.0f;
        #pragma unroll
        for (int e = 0; e < 9; e++) {
            float h = expf(t[e] - mx);
            s += h;
            sx += h * (float)(e % 3 - 1);
            sy += h * (float)(e / 3 - 1);
        }
        cxy[tid * 2 + 0] = sx / s;
        cxy[tid * 2 + 1] = sy / s;
    }
    __syncthreads();

    // ---- outputs ----
    if (tid == 0) {
        float glx = (float)(il & 7) - 3.5f, gly = (float)(il >> 3) - 3.5f;
        float grx = (float)(ir & 7) - 3.5f, gry = (float)(ir >> 3) - 3.5f;
        float cwx = cxy[0], cwy = cxy[1];   // from cff window  (coords / coords_e)
        float crx = cxy[2], cry = cxy[3];   // from cffr window (coords_r / coords_er)
        // expec0_out = expec0 + grid[il]*8 + coords_er*8
        out[4 * Nm + 2 * m + 0] = expec0[2 * m + 0] + glx * 8.0f + crx * 8.0f;
        out[4 * Nm + 2 * m + 1] = expec0[2 * m + 1] + gly * 8.0f + cry * 8.0f;
        // expec1_out = expec1 + grid[ir]*8 + coords_e*8
        out[4 * Nm + 2 * M + 2 * m + 0] = expec1[2 * m + 0] + grx * 8.0f + cwx * 8.0f;
        out[4 * Nm + 2 * M + 2 * m + 1] = expec1[2 * m + 1] + gry * 8.0f + cwy * 8.0f;
        if (m < Nm) {
            out[2 * m + 0] = mkpts0[2 * m + 0] + glx * 8.0f + crx * 8.0f;
            out[2 * m + 1] = mkpts0[2 * m + 1] + gly * 8.0f + cry * 8.0f;
            out[2 * Nm + 2 * m + 0] = mkpts1[2 * m + 0] + grx * 8.0f + cwx * 8.0f;
            out[2 * Nm + 2 * m + 1] = mkpts1[2 * m + 1] + gry * 8.0f + cwy * 8.0f;
        }
    }
}

extern "C" void kernel_launch(void* const* d_in, const int* in_sizes, int n_in,
                              void* d_out, int out_size, void* d_ws, size_t ws_size,
                              hipStream_t stream) {
    const float* feat0 = (const float*)d_in[0];
    const float* feat1 = (const float*)d_in[1];
    const float* mk0   = (const float*)d_in[2];
    const float* mk1   = (const float*)d_in[3];
    const float* e0    = (const float*)d_in[4];
    const float* e1    = (const float*)d_in[5];
    const int Nm = in_sizes[2] / 2;
    const int M  = in_sizes[4] / 2;
    float* out = (float*)d_out;
    hipLaunchKernelGGL(fine_matching_kernel, dim3(M), dim3(NTHREADS), 0, stream,
                       feat0, feat1, mk0, mk1, e0, e1, out, M, Nm);
}

// Round 3
// 538.179 us; speedup vs baseline: 1.2907x; 1.2907x over previous
//
#include <hip/hip_runtime.h>
#include <math.h>

// FineMatching: per-m (4096) fused GEMM(64x100x120) + dual-softmax argmax +
// 3x3 tail-channel window softmax + spatial expectation.
// Structure: 320 thr/block, 1 block per m. k-chunked LDS staging (3 x 40ch),
// C kept in registers (4x5 tile/thread), stats scratch aliased over chunk bufs.
#define NTHREADS 320
#define LCH 44           // chunk row stride (floats) = 11 float4; 11 odd -> spread groups
#define LCH4 11
#define CHUNK 40
#define NCHUNK 3

// LDS pool offsets (floats)
#define OFF_ACH   0                 // [64][44]  = 2816
#define OFF_BCH   2816              // [100][44] = 4400
#define OFF_ATAIL 7216              // [64][8]   = 512
#define OFF_BTAIL 7728              // [100][8]  = 800
#define OFF_LRS   8528              // [64]  log(row sum)
#define OFF_LCS   8592              // [100] log(col sum)
#define OFF_WV    8692              // [8]  per-wave argmax value
#define OFF_WIN   8700              // [18]
#define OFF_CXY   8718              // [4]
#define POOLSZ    8722

__global__ __launch_bounds__(NTHREADS, 4) void fine_matching_kernel(
    const float* __restrict__ feat0,   // [M][64][128]
    const float* __restrict__ feat1,   // [M][100][128]
    const float* __restrict__ mkpts0,  // [Nm][2]
    const float* __restrict__ mkpts1,  // [Nm][2]
    const float* __restrict__ expec0,  // [M][2]
    const float* __restrict__ expec1,  // [M][2]
    float* __restrict__ out,           // 4*Nm + 4*M floats
    int M, int Nm)
{
    __shared__ __align__(16) float pool[POOLSZ];
    __shared__ int wq[8];
    __shared__ int bestLK[2];

    float* Ach   = pool + OFF_ACH;
    float* Bch   = pool + OFF_BCH;
    float* Atail = pool + OFF_ATAIL;
    float* Btail = pool + OFF_BTAIL;
    float* lrs   = pool + OFF_LRS;
    float* lcs   = pool + OFF_LCS;
    float* wv    = pool + OFF_WV;
    float* win   = pool + OFF_WIN;
    float* cxy   = pool + OFF_CXY;
    // stats scratch aliased over dead chunk buffers (valid after last GEMM sync)
    float* rowpart = Ach;   // [64][20]  = 1280 <= 2816
    float* colpart = Bch;   // [100][16] = 1600 <= 4400

    const int m = blockIdx.x;
    const int tid = threadIdx.x;
    const float* f0 = feat0 + (size_t)m * (64 * 128);
    const float* f1 = feat1 + (size_t)m * (100 * 128);

    const int lg = tid / 20, rg = tid % 20;   // 16 x 20 thread grid
    const int l0 = lg * 4, r0 = rg * 5;

    float acc[4][5];
    #pragma unroll
    for (int a = 0; a < 4; a++)
        #pragma unroll
        for (int b = 0; b < 5; b++) acc[a][b] = 0.0f;

    // ---- k-chunked: stage -> GEMM -> sync ----
    for (int ch = 0; ch < NCHUNK; ++ch) {
        const int c0 = ch * CHUNK;
        for (int i = tid; i < 1640; i += NTHREADS) {
            if (i < 640) {
                int row = i / 10, c4 = i % 10;
                ((float4*)Ach)[row * LCH4 + c4] =
                    *(const float4*)(f0 + row * 128 + c0 + c4 * 4);
            } else {
                int j = i - 640;
                int row = j / 10, c4 = j % 10;
                ((float4*)Bch)[row * LCH4 + c4] =
                    *(const float4*)(f1 + row * 128 + c0 + c4 * 4);
            }
        }
        if (ch == 0) {
            // stage tail channels 120..127 once
            for (int i = tid; i < 328; i += NTHREADS) {
                if (i < 128)
                    ((float4*)Atail)[i] = *(const float4*)(f0 + (i >> 1) * 128 + 120 + (i & 1) * 4);
                else {
                    int j = i - 128;
                    ((float4*)Btail)[j] = *(const float4*)(f1 + (j >> 1) * 128 + 120 + (j & 1) * 4);
                }
            }
        }
        __syncthreads();

        const float4* A0 = (const float4*)(Ach + (l0 + 0) * LCH);
        const float4* A1 = (const float4*)(Ach + (l0 + 1) * LCH);
        const float4* A2 = (const float4*)(Ach + (l0 + 2) * LCH);
        const float4* A3 = (const float4*)(Ach + (l0 + 3) * LCH);
        const float4* B0 = (const float4*)(Bch + (r0 + 0) * LCH);
        const float4* B1 = (const float4*)(Bch + (r0 + 1) * LCH);
        const float4* B2 = (const float4*)(Bch + (r0 + 2) * LCH);
        const float4* B3 = (const float4*)(Bch + (r0 + 3) * LCH);
        const float4* B4 = (const float4*)(Bch + (r0 + 4) * LCH);
        #pragma unroll
        for (int c4 = 0; c4 < 10; ++c4) {
            float4 a0 = A0[c4], a1 = A1[c4], a2 = A2[c4], a3 = A3[c4];
            float4 b0 = B0[c4], b1 = B1[c4], b2 = B2[c4], b3 = B3[c4], b4 = B4[c4];
            #define FMA4(ACC, AV, BV) \
                ACC = fmaf(AV.x, BV.x, ACC); ACC = fmaf(AV.y, BV.y, ACC); \
                ACC = fmaf(AV.z, BV.z, ACC); ACC = fmaf(AV.w, BV.w, ACC);
            FMA4(acc[0][0], a0, b0) FMA4(acc[0][1], a0, b1) FMA4(acc[0][2], a0, b2)
            FMA4(acc[0][3], a0, b3) FMA4(acc[0][4], a0, b4)
            FMA4(acc[1][0], a1, b0) FMA4(acc[1][1], a1, b1) FMA4(acc[1][2], a1, b2)
            FMA4(acc[1][3], a1, b3) FMA4(acc[1][4], a1, b4)
            FMA4(acc[2][0], a2, b0) FMA4(acc[2][1], a2, b1) FMA4(acc[2][2], a2, b2)
            FMA4(acc[2][3], a2, b3) FMA4(acc[2][4], a2, b4)
            FMA4(acc[3][0], a3, b0) FMA4(acc[3][1], a3, b1) FMA4(acc[3][2], a3, b2)
            FMA4(acc[3][3], a3, b3) FMA4(acc[3][4], a3, b4)
            #undef FMA4
        }
        __syncthreads();   // chunk buffers dead; safe to restage / use as scratch
    }

    // ---- finalize conf values ----
    const float sc = 1.0f / 128.0f;
    #pragma unroll
    for (int a = 0; a < 4; a++)
        #pragma unroll
        for (int b = 0; b < 5; b++) acc[a][b] *= sc;

    // ---- dual-softmax stats, no max-subtraction (|x| << 1, exp safe) ----
    // softmax_r(x)*softmax_l(x) = exp(2x) / (rowsum * colsum); argmax in log domain.
    {
        float e[4][5];
        #pragma unroll
        for (int a = 0; a < 4; a++)
            #pragma unroll
            for (int b = 0; b < 5; b++) e[a][b] = __expf(acc[a][b]);
        #pragma unroll
        for (int a = 0; a < 4; a++) {
            float s = e[a][0] + e[a][1] + e[a][2] + e[a][3] + e[a][4];
            rowpart[(l0 + a) * 20 + rg] = s;
        }
        #pragma unroll
        for (int b = 0; b < 5; b++) {
            float s = e[0][b] + e[1][b] + e[2][b] + e[3][b];
            colpart[(r0 + b) * 16 + lg] = s;
        }
    }
    __syncthreads();
    if (tid < 64) {
        const float* p = &rowpart[tid * 20];
        float s = 0.0f;
        #pragma unroll
        for (int i = 0; i < 20; i++) s += p[i];
        lrs[tid] = __logf(s);
    } else if (tid < 164) {
        const int r = tid - 64;
        const float* p = &colpart[r * 16];
        float s = 0.0f;
        #pragma unroll
        for (int i = 0; i < 16; i++) s += p[i];
        lcs[r] = __logf(s);
    }
    __syncthreads();

    // ---- argmax over interior cells: score = 2x - log(rs) - log(cs) ----
    {
        float rl[4], cl[5];
        #pragma unroll
        for (int a = 0; a < 4; a++) rl[a] = lrs[l0 + a];
        #pragma unroll
        for (int b = 0; b < 5; b++) cl[b] = lcs[r0 + b];

        float bs = -INFINITY;
        int bq = 0x7fffffff;
        #pragma unroll
        for (int a = 0; a < 4; a++) {
            const int l = l0 + a;
            #pragma unroll
            for (int b = 0; b < 5; b++) {
                const int r = r0 + b;
                const int iq = r / 10, jq = r % 10;
                if (iq >= 1 && iq <= 8 && jq >= 1 && jq <= 8) {
                    float s = 2.0f * acc[a][b] - rl[a] - cl[b];
                    int q = l * 64 + (iq - 1) * 8 + (jq - 1);
                    if (s > bs || (s == bs && q < bq)) { bs = s; bq = q; }
                }
            }
        }
        #pragma unroll
        for (int off = 32; off > 0; off >>= 1) {
            float s2 = __shfl_xor(bs, off);
            int q2 = __shfl_xor(bq, off);
            if (s2 > bs || (s2 == bs && q2 < bq)) { bs = s2; bq = q2; }
        }
        const int wid = tid >> 6;
        if ((tid & 63) == 0) { wv[wid] = bs; wq[wid] = bq; }
    }
    __syncthreads();
    if (tid == 0) {
        float s = wv[0]; int q = wq[0];
        #pragma unroll
        for (int i = 1; i < 5; i++)
            if (wv[i] > s || (wv[i] == s && wq[i] < q)) { s = wv[i]; q = wq[i]; }
        bestLK[0] = q >> 6; bestLK[1] = q & 63;
    }
    __syncthreads();

    // ---- 3x3 local windows on tail channels ----
    const int il = bestLK[0], ir = bestLK[1];
    if (tid < 18) {
        const int wsel = tid / 9, e = tid % 9;
        const int dy = e / 3 - 1, dx = e % 3 - 1;
        const float* pa; const float* pb;
        if (wsel == 0) {
            int ii = (ir / 8 + dy + 10) % 10;
            int jj = (ir % 8 + dx + 10) % 10;
            pa = Atail + il * 8;
            pb = Btail + (ii * 10 + jj) * 8;
        } else {
            int ii = (il / 8 + dy + 10) % 10;
            int jj = (il % 8 + dx + 10) % 10;
            int p = ir * 100 + ii * 10 + jj;   // cffr flat index over (100,64)
            pa = Btail + (p >> 6) * 8;
            pb = Atail + (p & 63) * 8;
        }
        float val = 0.0f;
        #pragma unroll
        for (int c = 0; c < 8; c++) val = fmaf(pa[c], pb[c], val);
        win[tid] = val * 0.35355339059327373f;   // 1/sqrt(8)
    }
    __syncthreads();
    if (tid < 2) {
        const float* wvp = &win[tid * 9];
        float t[9]; float mx = -INFINITY;
        #pragma unroll
        for (int e = 0; e < 9; e++) { t[e] = wvp[e] * 0.1f; mx = fmaxf(mx, t[e]); }
        float s = 0.0f, sx = 0.0f, sy = 0.0f;
        #pragma unroll
        for (int e = 0; e < 9; e++) {
            float h = __expf(t[e] - mx);
            s += h;
            sx += h * (float)(e % 3 - 1);
            sy += h * (float)(e / 3 - 1);
        }
        cxy[tid * 2 + 0] = sx / s;
        cxy[tid * 2 + 1] = sy / s;
    }
    __syncthreads();

    // ---- outputs ----
    if (tid == 0) {
        float glx = (float)(il & 7) - 3.5f, gly = (float)(il >> 3) - 3.5f;
        float grx = (float)(ir & 7) - 3.5f, gry = (float)(ir >> 3) - 3.5f;
        float cwx = cxy[0], cwy = cxy[1];   // cff window  (coords / coords_e)
        float crx = cxy[2], cry = cxy[3];   // cffr window (coords_r / coords_er)
        out[4 * Nm + 2 * m + 0] = expec0[2 * m + 0] + glx * 8.0f + crx * 8.0f;
        out[4 * Nm + 2 * m + 1] = expec0[2 * m + 1] + gly * 8.0f + cry * 8.0f;
        out[4 * Nm + 2 * M + 2 * m + 0] = expec1[2 * m + 0] + grx * 8.0f + cwx * 8.0f;
        out[4 * Nm + 2 * M + 2 * m + 1] = expec1[2 * m + 1] + gry * 8.0f + cwy * 8.0f;
        if (m < Nm) {
            out[2 * m + 0] = mkpts0[2 * m + 0] + glx * 8.0f + crx * 8.0f;
            out[2 * m + 1] = mkpts0[2 * m + 1] + gly * 8.0f + cry * 8.0f;
            out[2 * Nm + 2 * m + 0] = mkpts1[2 * m + 0] + grx * 8.0f + cwx * 8.0f;
            out[2 * Nm + 2 * m + 1] = mkpts1[2 * m + 1] + gry * 8.0f + cwy * 8.0f;
        }
    }
}

extern "C" void kernel_launch(void* const* d_in, const int* in_sizes, int n_in,
                              void* d_out, int out_size, void* d_ws, size_t ws_size,
                              hipStream_t stream) {
    const float* feat0 = (const float*)d_in[0];
    const float* feat1 = (const float*)d_in[1];
    const float* mk0   = (const float*)d_in[2];
    const float* mk1   = (const float*)d_in[3];
    const float* e0    = (const float*)d_in[4];
    const float* e1    = (const float*)d_in[5];
    const int Nm = in_sizes[2] / 2;
    const int M  = in_sizes[4] / 2;
    float* out = (float*)d_out;
    hipLaunchKernelGGL(fine_matching_kernel, dim3(M), dim3(NTHREADS), 0, stream,
                       feat0, feat1, mk0, mk1, e0, e1, out, M, Nm);
}

// Round 5
// 403.899 us; speedup vs baseline: 1.7198x; 1.3325x over previous
//
#include <hip/hip_runtime.h>
#include <math.h>

// FineMatching via bf16x3 MFMA: conf = ah*bh + ah*bl + al*bh (fp32 accum),
// error ~1e-7 on conf (al*bl dropped ~2^-18 per term) — fp32-reorder level.
// Block = 256 thr (4 waves) per m. Wave w owns rows [16w,16w+16) x N=112
// (7 tiles of 16, rows 100..111 zero-padded). K chunked 4x32 in LDS.
#define NT 256
#define LDK 40           // bf16 row stride (32 data + 8 pad) -> 2-way max bank alias
#define POOLB 33936

typedef __attribute__((ext_vector_type(8))) short bf16x8;
typedef __attribute__((ext_vector_type(4))) float f32x4;

__device__ inline unsigned short f2bf(float x) {           // RNE, no NaN in data
    unsigned u = __float_as_uint(x);
    return (unsigned short)((u + 0x7fffu + ((u >> 16) & 1u)) >> 16);
}
__device__ inline float bf2f(unsigned short h) {
    return __uint_as_float(((unsigned)h) << 16);
}

__global__ __launch_bounds__(NT, 4) void fine_matching_kernel(
    const float* __restrict__ feat0,   // [M][64][128]
    const float* __restrict__ feat1,   // [M][100][128]
    const float* __restrict__ mkpts0,  // [Nm][2]
    const float* __restrict__ mkpts1,  // [Nm][2]
    const float* __restrict__ expec0,  // [M][2]
    const float* __restrict__ expec1,  // [M][2]
    float* __restrict__ out,
    int M, int Nm)
{
    __shared__ __align__(16) unsigned char pool[POOLB];
    unsigned short* AhU = (unsigned short*)(pool + 0);      // [64][40]
    unsigned short* AlU = (unsigned short*)(pool + 5120);   // [64][40]
    unsigned short* BhU = (unsigned short*)(pool + 10240);  // [112][40]
    unsigned short* BlU = (unsigned short*)(pool + 19200);  // [112][40]
    float* Atail = (float*)(pool + 28160);                  // [64][8]
    float* Btail = (float*)(pool + 30208);                  // [100][8]
    float* lcs   = (float*)(pool + 33408);                  // [100]
    float* wvp   = (float*)(pool + 33808);                  // [4]
    int*   wqp   = (int*)  (pool + 33824);                  // [4]
    float* win   = (float*)(pool + 33840);                  // [18]
    float* cxy   = (float*)(pool + 33912);                  // [4]
    int*   bestp = (int*)  (pool + 33928);                  // [2]
    float* colp  = (float*)(pool + 0);  // alias over AhU after GEMM: [100][4]

    const int m = blockIdx.x;
    const int tid = threadIdx.x;
    const int lane = tid & 63;
    const int wid = tid >> 6;
    const int lane_c = lane & 15;       // C/D col within tile; frag row select
    const int lane_g = lane >> 4;       // C/D row group; frag k-group
    const int strip = wid * 16;         // rows owned by this wave

    const float* f0 = feat0 + (size_t)m * (64 * 128);
    const float* f1 = feat1 + (size_t)m * (100 * 128);

    f32x4 acc[7];
    #pragma unroll
    for (int t = 0; t < 7; ++t) { acc[t][0] = 0.f; acc[t][1] = 0.f; acc[t][2] = 0.f; acc[t][3] = 0.f; }

    for (int ch = 0; ch < 4; ++ch) {
        if (ch) __syncthreads();   // prev chunk compute done before overwrite
        const int c0 = ch * 32;
        // ---- stage chunk: fp32 -> (bf16 hi, bf16 lo), zero ch>=120 & rows>=100 ----
        for (int i = tid; i < 1408; i += NT) {
            const bool isA = i < 512;
            const int j = isA ? i : i - 512;
            const int row = j >> 3, c4 = j & 7;
            const int gch = c0 + c4 * 4;
            float4 v = {0.f, 0.f, 0.f, 0.f};
            if (gch < 120) {
                if (isA) v = *(const float4*)(f0 + row * 128 + gch);
                else if (row < 100) v = *(const float4*)(f1 + row * 128 + gch);
            }
            ushort4 hh, ll;
            hh.x = f2bf(v.x); ll.x = f2bf(v.x - bf2f(hh.x));
            hh.y = f2bf(v.y); ll.y = f2bf(v.y - bf2f(hh.y));
            hh.z = f2bf(v.z); ll.z = f2bf(v.z - bf2f(hh.z));
            hh.w = f2bf(v.w); ll.w = f2bf(v.w - bf2f(hh.w));
            unsigned short* dh = (isA ? AhU : BhU) + row * LDK + c4 * 4;
            unsigned short* dl = (isA ? AlU : BlU) + row * LDK + c4 * 4;
            *(ushort4*)dh = hh;
            *(ushort4*)dl = ll;
        }
        if (ch == 0) {
            // tail channels 120..127 in fp32, staged once
            for (int i = tid; i < 328; i += NT) {
                if (i < 128) {
                    int row = i >> 1, half = i & 1;
                    *(float4*)(Atail + row * 8 + half * 4) =
                        *(const float4*)(f0 + row * 128 + 120 + half * 4);
                } else {
                    int j = i - 128;
                    int row = j >> 1, half = j & 1;
                    *(float4*)(Btail + row * 8 + half * 4) =
                        *(const float4*)(f1 + row * 128 + 120 + half * 4);
                }
            }
        }
        __syncthreads();

        // ---- MFMA: strip rows x 7 N-tiles, K=32 ----
        const int koff = lane_g * 8;
        const bf16x8 ah = *(const bf16x8*)(AhU + (strip + lane_c) * LDK + koff);
        const bf16x8 al = *(const bf16x8*)(AlU + (strip + lane_c) * LDK + koff);
        #pragma unroll
        for (int t = 0; t < 7; ++t) {
            const int brow = t * 16 + lane_c;
            const bf16x8 bh = *(const bf16x8*)(BhU + brow * LDK + koff);
            const bf16x8 bl = *(const bf16x8*)(BlU + brow * LDK + koff);
            acc[t] = __builtin_amdgcn_mfma_f32_16x16x32_bf16(ah, bh, acc[t], 0, 0, 0);
            acc[t] = __builtin_amdgcn_mfma_f32_16x16x32_bf16(ah, bl, acc[t], 0, 0, 0);
            acc[t] = __builtin_amdgcn_mfma_f32_16x16x32_bf16(al, bh, acc[t], 0, 0, 0);
        }
    }

    // ---- fused exp + row/col sums from C-fragments ----
    // C/D layout (m89): value (t,g) = conf[l = strip + lane_g*4 + g][r = t*16 + lane_c]
    const float invc = 1.0f / 128.0f;
    float xv[7][4];
    float rs[4] = {0.f, 0.f, 0.f, 0.f};
    float cs[7];
    #pragma unroll
    for (int t = 0; t < 7; ++t) {
        float c = 0.f;
        const bool colok = (t < 6) || (lane_c < 4);   // r = t*16+lane_c < 100
        #pragma unroll
        for (int g = 0; g < 4; ++g) {
            float x = acc[t][g] * invc;
            xv[t][g] = x;
            float ev = __expf(x);
            c += ev;
            if (colok) rs[g] += ev;
        }
        cs[t] = c;
    }
    #pragma unroll
    for (int g = 0; g < 4; ++g) {   // reduce across the 16 cols held by 16 lanes
        rs[g] += __shfl_xor(rs[g], 1);
        rs[g] += __shfl_xor(rs[g], 2);
        rs[g] += __shfl_xor(rs[g], 4);
        rs[g] += __shfl_xor(rs[g], 8);
    }
    float lrsv[4];
    #pragma unroll
    for (int g = 0; g < 4; ++g) lrsv[g] = __logf(rs[g]);
    #pragma unroll
    for (int t = 0; t < 7; ++t) {   // reduce across the 4 row-groups of this wave
        cs[t] += __shfl_xor(cs[t], 16);
        cs[t] += __shfl_xor(cs[t], 32);
    }
    __syncthreads();                 // all waves past MFMA; Ah region reusable
    if (lane_g == 0) {
        #pragma unroll
        for (int t = 0; t < 7; ++t) {
            int r = t * 16 + lane_c;
            if (r < 100) colp[r * 4 + wid] = cs[t];
        }
    }
    __syncthreads();
    if (tid < 100)
        lcs[tid] = __logf(colp[4 * tid] + colp[4 * tid + 1] + colp[4 * tid + 2] + colp[4 * tid + 3]);
    __syncthreads();

    // ---- argmax: score = 2x - log(rowsum) - log(colsum), first-index ties ----
    {
        float bs = -INFINITY; int bq = 0x7fffffff;
        #pragma unroll
        for (int t = 0; t < 7; ++t) {
            const int r = t * 16 + lane_c;
            if (r < 100) {
                const int iq = r / 10, jq = r - iq * 10;
                if (iq >= 1 && iq <= 8 && jq >= 1 && jq <= 8) {
                    const float lc = lcs[r];
                    const int qb = (iq - 1) * 8 + (jq - 1);
                    #pragma unroll
                    for (int g = 0; g < 4; ++g) {
                        float s = 2.0f * xv[t][g] - lrsv[g] - lc;
                        int q = (strip + lane_g * 4 + g) * 64 + qb;
                        if (s > bs || (s == bs && q < bq)) { bs = s; bq = q; }
                    }
                }
            }
        }
        #pragma unroll
        for (int off = 32; off > 0; off >>= 1) {
            float s2 = __shfl_xor(bs, off);
            int q2 = __shfl_xor(bq, off);
            if (s2 > bs || (s2 == bs && q2 < bq)) { bs = s2; bq = q2; }
        }
        if (lane == 0) { wvp[wid] = bs; wqp[wid] = bq; }
    }
    __syncthreads();
    if (tid == 0) {
        float s = wvp[0]; int q = wqp[0];
        #pragma unroll
        for (int i = 1; i < 4; ++i)
            if (wvp[i] > s || (wvp[i] == s && wqp[i] < q)) { s = wvp[i]; q = wqp[i]; }
        bestp[0] = q >> 6; bestp[1] = q & 63;
    }
    __syncthreads();

    // ---- 3x3 tail-channel windows ----
    const int il = bestp[0], ir = bestp[1];
    if (tid < 18) {
        const int wsel = tid / 9, e = tid % 9;
        const int dy = e / 3 - 1, dx = e % 3 - 1;
        const float* pa; const float* pb;
        if (wsel == 0) {
            int ii = (ir / 8 + dy + 10) % 10;
            int jj = (ir % 8 + dx + 10) % 10;
            pa = Atail + il * 8;
            pb = Btail + (ii * 10 + jj) * 8;
        } else {
            int ii = (il / 8 + dy + 10) % 10;
            int jj = (il % 8 + dx + 10) % 10;
            int p = ir * 100 + ii * 10 + jj;   // cffr flat index over (100,64)
            pa = Btail + (p >> 6) * 8;
            pb = Atail + (p & 63) * 8;
        }
        float val = 0.0f;
        #pragma unroll
        for (int c = 0; c < 8; c++) val = fmaf(pa[c], pb[c], val);
        win[tid] = val * 0.35355339059327373f;   // 1/sqrt(8)
    }
    __syncthreads();
    if (tid < 2) {
        const float* wp = &win[tid * 9];
        float t[9]; float mx = -INFINITY;
        #pragma unroll
        for (int e = 0; e < 9; e++) { t[e] = wp[e] * 0.1f; mx = fmaxf(mx, t[e]); }
        float s = 0.f, sx = 0.f, sy = 0.f;
        #pragma unroll
        for (int e = 0; e < 9; e++) {
            float h = __expf(t[e] - mx);
            s += h;
            sx += h * (float)(e % 3 - 1);
            sy += h * (float)(e / 3 - 1);
        }
        cxy[tid * 2 + 0] = sx / s;
        cxy[tid * 2 + 1] = sy / s;
    }
    __syncthreads();

    // ---- outputs ----
    if (tid == 0) {
        float glx = (float)(il & 7) - 3.5f, gly = (float)(il >> 3) - 3.5f;
        float grx = (float)(ir & 7) - 3.5f, gry = (float)(ir >> 3) - 3.5f;
        float cwx = cxy[0], cwy = cxy[1];   // cff window  (coords / coords_e)
        float crx = cxy[2], cry = cxy[3];   // cffr window (coords_r / coords_er)
        out[4 * Nm + 2 * m + 0] = expec0[2 * m + 0] + glx * 8.0f + crx * 8.0f;
        out[4 * Nm + 2 * m + 1] = expec0[2 * m + 1] + gly * 8.0f + cry * 8.0f;
        out[4 * Nm + 2 * M + 2 * m + 0] = expec1[2 * m + 0] + grx * 8.0f + cwx * 8.0f;
        out[4 * Nm + 2 * M + 2 * m + 1] = expec1[2 * m + 1] + gry * 8.0f + cwy * 8.0f;
        if (m < Nm) {
            out[2 * m + 0] = mkpts0[2 * m + 0] + glx * 8.0f + crx * 8.0f;
            out[2 * m + 1] = mkpts0[2 * m + 1] + gly * 8.0f + cry * 8.0f;
            out[2 * Nm + 2 * m + 0] = mkpts1[2 * m + 0] + grx * 8.0f + cwx * 8.0f;
            out[2 * Nm + 2 * m + 1] = mkpts1[2 * m + 1] + gry * 8.0f + cwy * 8.0f;
        }
    }
}

extern "C" void kernel_launch(void* const* d_in, const int* in_sizes, int n_in,
                              void* d_out, int out_size, void* d_ws, size_t ws_size,
                              hipStream_t stream) {
    const float* feat0 = (const float*)d_in[0];
    const float* feat1 = (const float*)d_in[1];
    const float* mk0   = (const float*)d_in[2];
    const float* mk1   = (const float*)d_in[3];
    const float* e0    = (const float*)d_in[4];
    const float* e1    = (const float*)d_in[5];
    const int Nm = in_sizes[2] / 2;
    const int M  = in_sizes[4] / 2;
    float* out = (float*)d_out;
    hipLaunchKernelGGL(fine_matching_kernel, dim3(M), dim3(NT), 0, stream,
                       feat0, feat1, mk0, mk1, e0, e1, out, M, Nm);
}